// Round 5
// baseline (197.504 us; speedup 1.0000x reference)
//
#include <hip/hip_runtime.h>

// DSAttention round 20 = r19 (CH=8, f-split fwd, fp16 prep w/ baked XOR
// swizzle, gl16 staging, 40960B LDS, 640 one-shot blocks) with:
//  1) comb FUSED into fwd: partials -> threadfence -> per-(bh,qt) atomic
//     counter (zeroed by prep) -> last-arriving chunk reduces+normalizes.
//     Deletes the comb kernel + launch gap; reduce overlaps stragglers.
//  2) item order retuned so round-robin CU assignment gives per-CU loads
//     (8,6,4)/(8,8,2)=18 or (8,8)=16 tiles vs r19's worst 20 (avg 17).
// Inner loops byte-identical to r19.

typedef _Float16 h8 __attribute__((ext_vector_type(8)));
typedef _Float16 h2 __attribute__((ext_vector_type(2)));
typedef float f32x4 __attribute__((ext_vector_type(4)));

constexpr int Bc = 2, Lc = 2048, Hc = 8, Ec = 64, Sc = 2048;
constexpr int QTL = 128;              // q rows per work item
constexpr int NQT = Lc / QTL;         // 16 q-tiles
constexpr int KT = 64;                // keys per staged tile
constexpr int NBH = Bc * Hc;          // 16
constexpr int CH = 8;                 // kt-tiles per chunk (512 keys)
constexpr int EPB = 40;               // sum of nch over 16 q-tiles (CH=8)
constexpr int NIT = NBH * EPB;        // 640 work items
constexpr float SCALE = 0.125f;
constexpr float LOG2E = 1.44269504088896340736f;

// exclusive prefix of nch(qt) = ceil((2*qt+2)/8) over qt ascending
__constant__ int d_qtbase[16] = {0,1,2,3,4,6,8,10,12,15,18,21,24,28,32,36};
// Balanced order (per bh, 40 items). With n-th per-XCD block -> CU n%32,
// rounds are: [0,16): 8-tile; [16,20): 6-tile; [20,32): 8-tile (rounds 1+2
// give CU0-7 8+6, CU8-31 8+8); [32,36): 4-tile; [36,40): 2-tile (round 3:
// CU0-7 +4, CU8-15 +2) => per-CU totals 18/18/16.
__constant__ signed char d_eqt[40] = {
  15,15,15,15, 14,14,14, 13,13,13, 12,12,12, 11,11,11,
  14,10, 6, 2,
  10,10, 9, 9, 8, 8, 7, 7, 6, 5, 4, 3,
  13, 9, 5, 1,
  12, 8, 4, 0};
__constant__ signed char d_ec0[40] = {
   0, 1, 2, 3,  0, 1, 2,  0, 1, 2,  0, 1, 2,  0, 1, 2,
   3, 2, 1, 0,
   0, 1, 0, 1, 0, 1, 0, 1, 0, 0, 0, 0,
   3, 2, 1, 0,
   3, 2, 1, 0};

__device__ __forceinline__ h2 pk2(float x, float y) {
  return __builtin_bit_cast(h2, __builtin_amdgcn_cvt_pkrtz(x, y));
}
template <int CTRL>
__device__ __forceinline__ float dpp_f(float x) {
  int r = __builtin_amdgcn_update_dpp(0, __builtin_bit_cast(int, x), CTRL, 0xF, 0xF, true);
  return __builtin_bit_cast(float, r);
}
__device__ __forceinline__ void gl16(const void* g, void* l) {
  __builtin_amdgcn_global_load_lds(
      (const __attribute__((address_space(1))) void*)g,
      (__attribute__((address_space(3))) void*)l, 16, 0, 0);
}

// ---------------- pre-pass: K/V -> fp16, V transposed+tile-blocked, ----------
// ---------------- XOR swizzle baked into layout; zeroes chunk counters -------
__global__ __launch_bounds__(256, 4)
void dsattn_prep(const float* __restrict__ Kg, const float* __restrict__ Vg,
                 _Float16* __restrict__ Kh, _Float16* __restrict__ Vh,
                 int* __restrict__ cnt) {
  __shared__ __align__(16) _Float16 T[64][72];   // V^T staging, 9216 B
  const int kt = (int)blockIdx.x;                // 0..31
  const int bh = (int)blockIdx.y;                // 0..15
  const int b = bh >> 3, h = bh & 7;
  const int tid = (int)threadIdx.x;
  const int sr = tid >> 2;                       // key row in tile, 0..63
  const int e0 = (tid & 3) << 4;                 // 16 elems per thread
  const int s = kt * KT + sr;

  if (kt == 0 && tid < NQT) cnt[bh * NQT + tid] = 0;   // poison -> 0 each iter

  // K: row-major [bh][s][e] halves, 128B rows, swizzled 16B slots
  {
    const float* kp = Kg + (((size_t)b * Sc + s) * Hc + h) * Ec + e0;
    float4 a0 = ((const float4*)kp)[0], a1 = ((const float4*)kp)[1];
    float4 a2 = ((const float4*)kp)[2], a3 = ((const float4*)kp)[3];
    union { h8 v; h2 c[4]; } u0, u1;
    u0.c[0] = pk2(a0.x, a0.y); u0.c[1] = pk2(a0.z, a0.w);
    u0.c[2] = pk2(a1.x, a1.y); u0.c[3] = pk2(a1.z, a1.w);
    u1.c[0] = pk2(a2.x, a2.y); u1.c[1] = pk2(a2.z, a2.w);
    u1.c[2] = pk2(a3.x, a3.y); u1.c[3] = pk2(a3.z, a3.w);
    char* out = (char*)Kh + (((size_t)bh * Sc + s) << 7);
    const int sl = e0 >> 3;
    const int rx = (sr & 7) << 4;
    *(h8*)(out + ((sl << 4) ^ rx)) = u0.v;
    *(h8*)(out + (((sl + 1) << 4) ^ rx)) = u1.v;
  }

  // V: transpose 64x64 tile via LDS, out layout [bh][kt][e][ks] swizzled
  {
    const float* vp = Vg + (((size_t)b * Sc + s) * Hc + h) * Ec + e0;
    float4 v0 = ((const float4*)vp)[0], v1 = ((const float4*)vp)[1];
    float4 v2 = ((const float4*)vp)[2], v3 = ((const float4*)vp)[3];
    const float ev[16] = {v0.x, v0.y, v0.z, v0.w, v1.x, v1.y, v1.z, v1.w,
                          v2.x, v2.y, v2.z, v2.w, v3.x, v3.y, v3.z, v3.w};
#pragma unroll
    for (int j = 0; j < 8; ++j) {
      h2 t = pk2(ev[2 * j], ev[2 * j + 1]);
      T[e0 + 2 * j][sr] = t[0];
      T[e0 + 2 * j + 1][sr] = t[1];
    }
  }
  __syncthreads();
  {
    const int er = tid >> 2;                     // e row 0..63
    const int k0 = (tid & 3) << 4;               // ks start
    h8 w0 = *(const h8*)&T[er][k0];
    h8 w1 = *(const h8*)&T[er][k0 + 8];
    char* out = (char*)Vh + (((size_t)bh * 32 + kt) << 13) + er * 128;
    const int sl = k0 >> 3;
    const int rx = (er & 7) << 4;
    *(h8*)(out + ((sl << 4) ^ rx)) = w0;
    *(h8*)(out + (((sl + 1) << 4) ^ rx)) = w1;
  }
}

// ---------------- main fwd: gl16 staging + fused last-chunk combine ----------
__global__ __launch_bounds__(256, 3)
void dsattn_fwd_main(const float* __restrict__ Qg, const _Float16* __restrict__ Kh,
                     const _Float16* __restrict__ Vh, const float* __restrict__ taug,
                     const float* __restrict__ deltag, float* __restrict__ Og,
                     _Float16* __restrict__ Opart, float* __restrict__ Lpart,
                     int* __restrict__ cnt) {
  __shared__ __align__(16) _Float16 Ks[2][KT * 64];   // 16384 B
  __shared__ __align__(16) _Float16 Vt[2][Ec * 64];   // 16384 B
  __shared__ __align__(16) _Float16 Pb[4][16 * 64];   //  8192 B -> 40960 total

  const int tid = (int)threadIdx.x;
  const int wave = tid >> 6, lane = tid & 63;
  const int quad = lane >> 4, l16 = lane & 15;
  _Float16* pb = &Pb[wave][0];
  const int lo = l16 & 1;
  const int pbase = (lo ? 32 : 0) + (l16 & ~1);
  // swizzled half-unit offsets (rows read by this lane always have row&7==l16&7)
  const int kx = (l16 & 7) << 3;
  const int koff0 = (quad * 8) ^ kx;
  const int koff1 = (quad * 8 + 32) ^ kx;

  h8 onesf;
#pragma unroll
  for (int j = 0; j < 8; ++j) onesf[j] = (_Float16)1.0f;

  for (int it = (int)blockIdx.x; it < NIT; it += (int)gridDim.x) {
    // XCD-paired decode: blocks with the same (bid%8) share 2 bh -> L2 locality
    const int xcd = it & 7;
    const int r_ = it >> 3;                 // < 80
    const int bh = (xcd << 1) | (r_ & 1);
    const int e = r_ >> 1;                  // < 40
    const int qt = d_eqt[e], c0 = d_ec0[e];
    const int ntiles = 2 * qt + 2;
    const int nch = (ntiles + CH - 1) / CH;
    const int ktBeg = c0 * CH;
    const int ktEnd = min(ktBeg + CH - 1, ntiles - 1);
    const int q0 = qt * QTL;
    const int b = bh >> 3, h = bh & 7;
    const float ct = taug[b] * (SCALE * LOG2E);

    // ---- Q A-fragments ----
    h8 qfrag[2][2];
#pragma unroll
    for (int f = 0; f < 2; ++f)
#pragma unroll
      for (int kk = 0; kk < 2; ++kk) {
        const float* qp = Qg + (((size_t)b * Lc + q0 + 32 * wave + 16 * f + l16) * Hc + h) * Ec
                         + quad * 8 + kk * 32;
        const float4* p = (const float4*)qp;
        union { h8 v; h2 c[4]; } u;
        float4 a0 = p[0], a1 = p[1];
        u.c[0] = pk2(a0.x, a0.y); u.c[1] = pk2(a0.z, a0.w);
        u.c[2] = pk2(a1.x, a1.y); u.c[3] = pk2(a1.z, a1.w);
        qfrag[f][kk] = u.v;
      }

    f32x4 Oacc[2][4], Osum[2];
#pragma unroll
    for (int f = 0; f < 2; ++f) {
#pragma unroll
      for (int nt = 0; nt < 4; ++nt) Oacc[f][nt] = (f32x4){0.f, 0.f, 0.f, 0.f};
      Osum[f] = (f32x4){0.f, 0.f, 0.f, 0.f};
    }
    float dcur[4];

    __syncthreads();   // previous item's LDS reads complete before restaging

    // ---- prologue: async-stage tile ktBeg into buffer 0 ----
    {
      const char* kg = (const char*)Kh + (((size_t)bh * Sc + (size_t)ktBeg * KT) << 7)
                       + wave * 2048 + lane * 16;
      const char* vg = (const char*)Vh + (((size_t)bh * 32 + ktBeg) << 13)
                       + wave * 2048 + lane * 16;
      char* kl = (char*)&Ks[0][0] + wave * 2048;
      char* vl = (char*)&Vt[0][0] + wave * 2048;
      gl16(kg, kl); gl16(kg + 1024, kl + 1024);
      gl16(vg, vl); gl16(vg + 1024, vl + 1024);
#pragma unroll
      for (int nt = 0; nt < 4; ++nt)
        dcur[nt] = deltag[(size_t)b * Sc + ktBeg * KT + nt * 16 + l16] * (SCALE * LOG2E);
    }

    for (int kt = ktBeg; kt <= ktEnd; ++kt) {
      const int cur = (kt - ktBeg) & 1;
      const bool pf = (kt < ktEnd);
      const int kbase = kt * KT;

      __syncthreads();   // buffer cur ready (compiler drains vmcnt at barrier)

      // ---- async-prefetch kt+1 into the other buffer ----
      float dn[4];
      if (pf) {
        const char* kg = (const char*)Kh + (((size_t)bh * Sc + (size_t)(kt + 1) * KT) << 7)
                         + wave * 2048 + lane * 16;
        const char* vg = (const char*)Vh + (((size_t)bh * 32 + kt + 1) << 13)
                         + wave * 2048 + lane * 16;
        char* kl = (char*)&Ks[cur ^ 1][0] + wave * 2048;
        char* vl = (char*)&Vt[cur ^ 1][0] + wave * 2048;
        gl16(kg, kl); gl16(kg + 1024, kl + 1024);
        gl16(vg, vl); gl16(vg + 1024, vl + 1024);
#pragma unroll
        for (int nt = 0; nt < 4; ++nt)
          dn[nt] = deltag[(size_t)b * Sc + (kt + 1) * KT + nt * 16 + l16];
      }

      const int wtop = q0 + 32 * wave + 31;
      if (kbase <= wtop) {
        // ---- per 16-row fragment: QK^T -> softmax -> PV (halved live S) ----
#pragma unroll
        for (int f = 0; f < 2; ++f) {
          f32x4 Sacc[4];
#pragma unroll
          for (int nt = 0; nt < 4; ++nt) Sacc[nt] = (f32x4){0.f, 0.f, 0.f, 0.f};
          __builtin_amdgcn_s_setprio(1);
#pragma unroll
          for (int kk = 0; kk < 2; ++kk) {
            const int ko = kk ? koff1 : koff0;
            h8 bf[4];
#pragma unroll
            for (int nt = 0; nt < 4; ++nt)
              bf[nt] = *(const h8*)&Ks[cur][(nt * 16 + l16) * 64 + ko];
#pragma unroll
            for (int nt = 0; nt < 4; ++nt)
              Sacc[nt] = __builtin_amdgcn_mfma_f32_16x16x32_f16(qfrag[f][kk], bf[nt], Sacc[nt], 0, 0, 0);
          }
          __builtin_amdgcn_s_setprio(0);

          const int fr0 = q0 + 32 * wave + 16 * f;
#pragma unroll
          for (int nt = 0; nt < 4; ++nt)
#pragma unroll
            for (int rr = 0; rr < 4; ++rr)
              Sacc[nt][rr] = Sacc[nt][rr] * ct + dcur[nt];
          if (kbase + 63 > fr0) {
#pragma unroll
            for (int nt = 0; nt < 4; ++nt) {
              const int key = kbase + nt * 16 + l16;
#pragma unroll
              for (int rr = 0; rr < 4; ++rr)
                if (key > fr0 + quad * 4 + rr) Sacc[nt][rr] = -1e30f;
            }
          }
#pragma unroll
          for (int nt = 0; nt < 4; ++nt)
#pragma unroll
            for (int rr = 0; rr < 4; ++rr)
              Sacc[nt][rr] = __builtin_amdgcn_exp2f(Sacc[nt][rr]);   // bounded

          // P -> Pb rows quad*4+rr (DPP xor1 pairing, packed h2, XOR slots)
#pragma unroll
          for (int rr = 0; rr < 4; ++rr) {
            float o0 = dpp_f<0xB1>(Sacc[0][rr]);
            float o1 = dpp_f<0xB1>(Sacc[1][rr]);
            float o2 = dpp_f<0xB1>(Sacc[2][rr]);
            float o3 = dpp_f<0xB1>(Sacc[3][rr]);
            h2 d0 = lo ? pk2(o2, Sacc[2][rr]) : pk2(Sacc[0][rr], o0);
            h2 d1 = lo ? pk2(o3, Sacc[3][rr]) : pk2(Sacc[1][rr], o1);
            const int row = (quad << 2) + rr;
            char* pr = (char*)pb + row * 128;
            const int rx = (row & 7) << 4;
            *(h2*)(pr + ((pbase * 2) ^ rx)) = d0;
            *(h2*)(pr + ((pbase * 2 + 32) ^ rx)) = d1;
          }
          asm volatile("s_waitcnt lgkmcnt(0)" ::: "memory");  // wave-local P RAW
          __builtin_amdgcn_sched_barrier(0);                  // rule #18 fence

          h8 af0 = *(const h8*)&pb[l16 * 64 + koff0];
          h8 af1 = *(const h8*)&pb[l16 * 64 + koff1];

          __builtin_amdgcn_s_setprio(1);
#pragma unroll
          for (int nt = 0; nt < 4; ++nt) {
            h8 vf0 = *(const h8*)&Vt[cur][(nt * 16 + l16) * 64 + koff0];
            Oacc[f][nt] = __builtin_amdgcn_mfma_f32_16x16x32_f16(af0, vf0, Oacc[f][nt], 0, 0, 0);
            h8 vf1 = *(const h8*)&Vt[cur][(nt * 16 + l16) * 64 + koff1];
            Oacc[f][nt] = __builtin_amdgcn_mfma_f32_16x16x32_f16(af1, vf1, Oacc[f][nt], 0, 0, 0);
          }
          Osum[f] = __builtin_amdgcn_mfma_f32_16x16x32_f16(af0, onesf, Osum[f], 0, 0, 0);
          Osum[f] = __builtin_amdgcn_mfma_f32_16x16x32_f16(af1, onesf, Osum[f], 0, 0, 0);
          __builtin_amdgcn_s_setprio(0);
        }
      }

      if (pf) {
#pragma unroll
        for (int nt = 0; nt < 4; ++nt) dcur[nt] = dn[nt] * (SCALE * LOG2E);
      }
    }

    // ---- epilogue ----
    if (nch == 1) {
#pragma unroll
      for (int f = 0; f < 2; ++f)
#pragma unroll
        for (int rr = 0; rr < 4; ++rr) {
          const int qrow = q0 + 32 * wave + 16 * f + (quad << 2) + rr;
          const float inv = 1.0f / Osum[f][rr];
          float* op = Og + (((size_t)b * Lc + qrow) * Hc + h) * Ec;
#pragma unroll
          for (int nt = 0; nt < 4; ++nt) op[nt * 16 + l16] = Oacc[f][nt][rr] * inv;
        }
    } else {
      const int base = bh * EPB + d_qtbase[qt];
      const int en = base + c0;
      _Float16* op = Opart + (size_t)en * (QTL * Ec);
#pragma unroll
      for (int f = 0; f < 2; ++f)
#pragma unroll
        for (int rr = 0; rr < 4; ++rr) {
          const int row = 32 * wave + 16 * f + (quad << 2) + rr;
#pragma unroll
          for (int nt = 0; nt < 4; ++nt)
            op[row * Ec + nt * 16 + l16] = (_Float16)Oacc[f][nt][rr];
          if (l16 == 0) Lpart[en * QTL + row] = Osum[f][rr];
        }

      // ---- fused combine: last-arriving chunk reduces + normalizes ----
      volatile int* s_flag = (volatile int*)&Pb[0][0];   // Pb free after loop
      __threadfence();                // partials device-visible (release)
      __syncthreads();                // all threads' stores + fences done
      if (tid == 0) {
        int old = atomicAdd(&cnt[bh * NQT + qt], 1);
        *s_flag = (old == nch - 1) ? 1 : 0;
      }
      __syncthreads();
      if (*s_flag) {
        __threadfence();              // acquire side: see other chunks' stores
        const int row0 = tid >> 3;            // 0..31
        const int col = (tid & 7) << 3;       // 8 cols
#pragma unroll
        for (int slab = 0; slab < 4; ++slab) {
          const int row = slab * 32 + row0;
          float acc[8];
#pragma unroll
          for (int i = 0; i < 8; ++i) acc[i] = 0.f;
          float l = 0.f;
          for (int c = 0; c < nch; ++c) {
            l += Lpart[(base + c) * QTL + row];
            h8 v = *(const h8*)(Opart + (size_t)(base + c) * (QTL * Ec) + row * Ec + col);
#pragma unroll
            for (int i = 0; i < 8; ++i) acc[i] += (float)v[i];
          }
          const float inv = 1.0f / l;
          float* out = Og + (((size_t)b * Lc + q0 + row) * Hc + h) * Ec + col;
          float4 o0, o1;
          o0.x = acc[0] * inv; o0.y = acc[1] * inv; o0.z = acc[2] * inv; o0.w = acc[3] * inv;
          o1.x = acc[4] * inv; o1.y = acc[5] * inv; o1.z = acc[6] * inv; o1.w = acc[7] * inv;
          ((float4*)out)[0] = o0;
          ((float4*)out)[1] = o1;
        }
      }
    }
  }
}

// ---------------- monolithic fallback (no workspace): old proven path --------
__global__ __launch_bounds__(256, 2)
void dsattn_fwd_mono(const float* __restrict__ Qg, const float* __restrict__ Kg,
                     const float* __restrict__ Vg, const float* __restrict__ taug,
                     const float* __restrict__ deltag, float* __restrict__ Og) {
  constexpr int LDK = 72;
  __shared__ __align__(16) _Float16 Ks[2][KT * LDK];
  __shared__ __align__(16) _Float16 Vt[2][Ec * LDK];
  __shared__ __align__(16) _Float16 Pb[4][16 * LDK];

  const int tid = (int)threadIdx.x;
  const int wave = tid >> 6, lane = tid & 63;
  const int quad = lane >> 4, l16 = lane & 15;
  const int srow = tid >> 2;
  const int sec = (tid & 3) << 4;
  const int vrp = ((tid >> 3) + 4 * (tid & 7)) & 31;
  const int ve8 = (tid & 7) << 3;
  _Float16* pb = &Pb[wave][0];
  const int lo = l16 & 1;
  const int pbase = (lo ? 32 : 0) + (l16 & ~1);

  h8 onesf;
#pragma unroll
  for (int j = 0; j < 8; ++j) onesf[j] = (_Float16)1.0f;

  for (int wid = (int)blockIdx.x; wid < NQT * NBH; wid += (int)gridDim.x) {
    const int bh = wid & (NBH - 1);
    const int qt = NQT - 1 - (wid >> 4);
    const int ktEnd = 2 * qt + 1;
    const int q0 = qt * QTL;
    const int b = bh >> 3, h = bh & 7;
    const float ct = taug[b] * (SCALE * LOG2E);

    h8 qfrag[2][2];
#pragma unroll
    for (int f = 0; f < 2; ++f)
#pragma unroll
      for (int kk = 0; kk < 2; ++kk) {
        const float* qp = Qg + (((size_t)b * Lc + q0 + 32 * wave + 16 * f + l16) * Hc + h) * Ec
                         + quad * 8 + kk * 32;
        const float4* p = (const float4*)qp;
        union { h8 v; h2 c[4]; } u;
        float4 a0 = p[0], a1 = p[1];
        u.c[0] = pk2(a0.x, a0.y); u.c[1] = pk2(a0.z, a0.w);
        u.c[2] = pk2(a1.x, a1.y); u.c[3] = pk2(a1.z, a1.w);
        qfrag[f][kk] = u.v;
      }

    f32x4 Oacc[2][4], Osum[2];
#pragma unroll
    for (int f = 0; f < 2; ++f) {
#pragma unroll
      for (int nt = 0; nt < 4; ++nt) Oacc[f][nt] = (f32x4){0.f, 0.f, 0.f, 0.f};
      Osum[f] = (f32x4){0.f, 0.f, 0.f, 0.f};
    }
    float dcur[4];

    __syncthreads();

    {
      const float* kp = Kg + (((size_t)b * Sc + srow) * Hc + h) * Ec + sec;
      float4 c0v = ((const float4*)kp)[0], c1v = ((const float4*)kp)[1];
      float4 c2v = ((const float4*)kp)[2], c3v = ((const float4*)kp)[3];
      const float* vp0 = Vg + (((size_t)b * Sc + 2 * vrp) * Hc + h) * Ec + ve8;
      const float* vp1 = vp0 + Hc * Ec;
      float4 r00 = ((const float4*)vp0)[0], r01 = ((const float4*)vp0)[1];
      float4 r10 = ((const float4*)vp1)[0], r11 = ((const float4*)vp1)[1];
#pragma unroll
      for (int nt = 0; nt < 4; ++nt)
        dcur[nt] = deltag[(size_t)b * Sc + nt * 16 + l16] * (SCALE * LOG2E);
      union { h8 v; h2 c[4]; } w0, w1;
      w0.c[0] = pk2(c0v.x, c0v.y); w0.c[1] = pk2(c0v.z, c0v.w);
      w0.c[2] = pk2(c1v.x, c1v.y); w0.c[3] = pk2(c1v.z, c1v.w);
      w1.c[0] = pk2(c2v.x, c2v.y); w1.c[1] = pk2(c2v.z, c2v.w);
      w1.c[2] = pk2(c3v.x, c3v.y); w1.c[3] = pk2(c3v.z, c3v.w);
      *(h8*)&Ks[0][srow * LDK + sec] = w0.v;
      *(h8*)&Ks[0][srow * LDK + sec + 8] = w1.v;
      const float e0[8] = {r00.x, r00.y, r00.z, r00.w, r01.x, r01.y, r01.z, r01.w};
      const float e1[8] = {r10.x, r10.y, r10.z, r10.w, r11.x, r11.y, r11.z, r11.w};
#pragma unroll
      for (int j = 0; j < 8; ++j)
        *(h2*)&Vt[0][(ve8 + j) * LDK + 2 * vrp] = pk2(e0[j], e1[j]);
    }

    for (int kt = 0; kt <= ktEnd; ++kt) {
      const int cur = kt & 1;
      const bool pf = (kt < ktEnd);
      const int kbase = kt * KT;

      __syncthreads();

      float4 kn0, kn1, kn2, kn3, vn00, vn01, vn10, vn11;
      float dn[4];
      if (pf) {
        const int nb = (kt + 1) * KT;
        const float* kp = Kg + (((size_t)b * Sc + nb + srow) * Hc + h) * Ec + sec;
        kn0 = ((const float4*)kp)[0]; kn1 = ((const float4*)kp)[1];
        kn2 = ((const float4*)kp)[2]; kn3 = ((const float4*)kp)[3];
        const float* vp0 = Vg + (((size_t)b * Sc + nb + 2 * vrp) * Hc + h) * Ec + ve8;
        const float* vp1 = vp0 + Hc * Ec;
        vn00 = ((const float4*)vp0)[0]; vn01 = ((const float4*)vp0)[1];
        vn10 = ((const float4*)vp1)[0]; vn11 = ((const float4*)vp1)[1];
#pragma unroll
        for (int nt = 0; nt < 4; ++nt)
          dn[nt] = deltag[(size_t)b * Sc + nb + nt * 16 + l16];
      }

      const int wtop = q0 + 32 * wave + 31;
      if (kbase <= wtop) {
        f32x4 Sacc[2][4];
#pragma unroll
        for (int f = 0; f < 2; ++f)
#pragma unroll
          for (int nt = 0; nt < 4; ++nt) Sacc[f][nt] = (f32x4){0.f, 0.f, 0.f, 0.f};
#pragma unroll
        for (int kk = 0; kk < 2; ++kk) {
          h8 bf[4];
#pragma unroll
          for (int nt = 0; nt < 4; ++nt)
            bf[nt] = *(const h8*)&Ks[cur][(nt * 16 + l16) * LDK + quad * 8 + kk * 32];
#pragma unroll
          for (int f = 0; f < 2; ++f)
#pragma unroll
            for (int nt = 0; nt < 4; ++nt)
              Sacc[f][nt] = __builtin_amdgcn_mfma_f32_16x16x32_f16(qfrag[f][kk], bf[nt], Sacc[f][nt], 0, 0, 0);
        }

#pragma unroll
        for (int f = 0; f < 2; ++f) {
          const int fr0 = q0 + 32 * wave + 16 * f;
          float sv[4][4];
#pragma unroll
          for (int nt = 0; nt < 4; ++nt)
#pragma unroll
            for (int rr = 0; rr < 4; ++rr)
              sv[nt][rr] = Sacc[f][nt][rr] * ct + dcur[nt];
          if (kbase + 63 > fr0) {
#pragma unroll
            for (int nt = 0; nt < 4; ++nt) {
              const int key = kbase + nt * 16 + l16;
#pragma unroll
              for (int rr = 0; rr < 4; ++rr)
                if (key > fr0 + quad * 4 + rr) sv[nt][rr] = -1e30f;
            }
          }
#pragma unroll
          for (int nt = 0; nt < 4; ++nt)
#pragma unroll
            for (int rr = 0; rr < 4; ++rr)
              sv[nt][rr] = __builtin_amdgcn_exp2f(sv[nt][rr]);

#pragma unroll
          for (int rr = 0; rr < 4; ++rr) {
            float o0 = dpp_f<0xB1>(sv[0][rr]);
            float o1 = dpp_f<0xB1>(sv[1][rr]);
            float o2 = dpp_f<0xB1>(sv[2][rr]);
            float o3 = dpp_f<0xB1>(sv[3][rr]);
            h2 d0 = lo ? pk2(o2, sv[2][rr]) : pk2(sv[0][rr], o0);
            h2 d1 = lo ? pk2(o3, sv[3][rr]) : pk2(sv[1][rr], o1);
            _Float16* pp = &pb[((quad << 2) + rr) * LDK + pbase];
            *(h2*)pp = d0;
            *(h2*)(pp + 16) = d1;
          }
          asm volatile("s_waitcnt lgkmcnt(0)" ::: "memory");

          h8 af0 = *(const h8*)&pb[l16 * LDK + quad * 8];
          h8 af1 = *(const h8*)&pb[l16 * LDK + quad * 8 + 32];

#pragma unroll
          for (int nt = 0; nt < 4; ++nt) {
            h8 vf0 = *(const h8*)&Vt[cur][(nt * 16 + l16) * LDK + quad * 8];
            Oacc[f][nt] = __builtin_amdgcn_mfma_f32_16x16x32_f16(af0, vf0, Oacc[f][nt], 0, 0, 0);
            h8 vf1 = *(const h8*)&Vt[cur][(nt * 16 + l16) * LDK + quad * 8 + 32];
            Oacc[f][nt] = __builtin_amdgcn_mfma_f32_16x16x32_f16(af1, vf1, Oacc[f][nt], 0, 0, 0);
          }
          Osum[f] = __builtin_amdgcn_mfma_f32_16x16x32_f16(af0, onesf, Osum[f], 0, 0, 0);
          Osum[f] = __builtin_amdgcn_mfma_f32_16x16x32_f16(af1, onesf, Osum[f], 0, 0, 0);
        }
      }

      if (pf) {
        _Float16* ksn = &Ks[cur ^ 1][0];
        _Float16* vtn = &Vt[cur ^ 1][0];
        union { h8 v; h2 c[4]; } w0, w1;
        w0.c[0] = pk2(kn0.x, kn0.y); w0.c[1] = pk2(kn0.z, kn0.w);
        w0.c[2] = pk2(kn1.x, kn1.y); w0.c[3] = pk2(kn1.z, kn1.w);
        w1.c[0] = pk2(kn2.x, kn2.y); w1.c[1] = pk2(kn2.z, kn2.w);
        w1.c[2] = pk2(kn3.x, kn3.y); w1.c[3] = pk2(kn3.z, kn3.w);
        *(h8*)&ksn[srow * LDK + sec] = w0.v;
        *(h8*)&ksn[srow * LDK + sec + 8] = w1.v;
        const float e0[8] = {vn00.x, vn00.y, vn00.z, vn00.w, vn01.x, vn01.y, vn01.z, vn01.w};
        const float e1[8] = {vn10.x, vn10.y, vn10.z, vn10.w, vn11.x, vn11.y, vn11.z, vn11.w};
#pragma unroll
        for (int j = 0; j < 8; ++j)
          *(h2*)&vtn[(ve8 + j) * LDK + 2 * vrp] = pk2(e0[j], e1[j]);
#pragma unroll
        for (int nt = 0; nt < 4; ++nt) dcur[nt] = dn[nt] * (SCALE * LOG2E);
      }
    }

#pragma unroll
    for (int f = 0; f < 2; ++f)
#pragma unroll
      for (int rr = 0; rr < 4; ++rr) {
        const int qrow = q0 + 32 * wave + 16 * f + (quad << 2) + rr;
        const float inv = 1.0f / Osum[f][rr];
        float* op = Og + (((size_t)b * Lc + qrow) * Hc + h) * Ec;
#pragma unroll
        for (int nt = 0; nt < 4; ++nt) op[nt * 16 + l16] = Oacc[f][nt][rr] * inv;
      }
  }
}

extern "C" void kernel_launch(void* const* d_in, const int* in_sizes, int n_in,
                              void* d_out, int out_size, void* d_ws, size_t ws_size,
                              hipStream_t stream) {
  const float* Q = (const float*)d_in[0];
  const float* K = (const float*)d_in[1];
  const float* V = (const float*)d_in[2];
  const float* tau = (const float*)d_in[3];
  const float* delta = (const float*)d_in[4];
  float* O = (float*)d_out;

  const size_t needOp = (size_t)NIT * QTL * Ec * 2;       // 10.49 MB
  const size_t needLp = (size_t)NIT * QTL * 4;            //  0.33 MB
  const size_t needKh = (size_t)NBH * Sc * Ec * 2;        //  4.19 MB
  const size_t needVh = needKh;                           //  4.19 MB
  const size_t needCnt = (size_t)NBH * NQT * 4;           //  1 KB
  const size_t need = needOp + needLp + needKh + needVh + needCnt;

  if (ws_size >= need) {
    _Float16* Opart = (_Float16*)d_ws;
    float* Lpart = (float*)((char*)d_ws + needOp);
    _Float16* Kh = (_Float16*)((char*)d_ws + needOp + needLp);
    _Float16* Vh = (_Float16*)((char*)d_ws + needOp + needLp + needKh);
    int* cnt = (int*)((char*)d_ws + needOp + needLp + needKh + needVh);
    dsattn_prep<<<dim3(Sc / KT, NBH), 256, 0, stream>>>(K, V, Kh, Vh, cnt);
    dsattn_fwd_main<<<dim3(NIT), 256, 0, stream>>>(Q, Kh, Vh, tau, delta, O,
                                                   Opart, Lpart, cnt);
  } else {
    dsattn_fwd_mono<<<dim3(NQT * NBH), 256, 0, stream>>>(Q, K, V, tau, delta, O);
  }
}

// Round 6
// 106.976 us; speedup vs baseline: 1.8463x; 1.8463x over previous
//
#include <hip/hip_runtime.h>

// DSAttention round 21 = revert r20's fused combine (per-item __threadfence
// = per-block L2 writeback/invalidate on gfx950 -> 4x uniform stretch,
// fwd 33->125us) back to r19's 3-kernel structure (verified 107us).
// Kept from r20: balanced item order (per-CU tile loads 18/18/16).
// New: fragment-layout Opart -- fwd epilogue stores 8x8B coalesced per
// thread (was 32x2B scalar); comb reads b64 per (row,chunk) and writes
// Og with coalesced 4B lanes. Same bytes, ~4x fewer epilogue/comb instrs.

typedef _Float16 h8 __attribute__((ext_vector_type(8)));
typedef _Float16 h2 __attribute__((ext_vector_type(2)));
typedef float f32x4 __attribute__((ext_vector_type(4)));

constexpr int Bc = 2, Lc = 2048, Hc = 8, Ec = 64, Sc = 2048;
constexpr int QTL = 128;              // q rows per work item
constexpr int NQT = Lc / QTL;         // 16 q-tiles
constexpr int KT = 64;                // keys per staged tile
constexpr int NBH = Bc * Hc;          // 16
constexpr int CH = 8;                 // kt-tiles per chunk (512 keys)
constexpr int EPB = 40;               // sum of nch over 16 q-tiles (CH=8)
constexpr int NIT = NBH * EPB;        // 640 work items
constexpr float SCALE = 0.125f;
constexpr float LOG2E = 1.44269504088896340736f;

// exclusive prefix of nch(qt) = ceil((2*qt+2)/8) over qt ascending
__constant__ int d_qtbase[16] = {0,1,2,3,4,6,8,10,12,15,18,21,24,28,32,36};
// Balanced order (per bh, 40 items): per-CU totals 18/18/16 tiles.
__constant__ signed char d_eqt[40] = {
  15,15,15,15, 14,14,14, 13,13,13, 12,12,12, 11,11,11,
  14,10, 6, 2,
  10,10, 9, 9, 8, 8, 7, 7, 6, 5, 4, 3,
  13, 9, 5, 1,
  12, 8, 4, 0};
__constant__ signed char d_ec0[40] = {
   0, 1, 2, 3,  0, 1, 2,  0, 1, 2,  0, 1, 2,  0, 1, 2,
   3, 2, 1, 0,
   0, 1, 0, 1, 0, 1, 0, 1, 0, 0, 0, 0,
   3, 2, 1, 0,
   3, 2, 1, 0};

__device__ __forceinline__ h2 pk2(float x, float y) {
  return __builtin_bit_cast(h2, __builtin_amdgcn_cvt_pkrtz(x, y));
}
template <int CTRL>
__device__ __forceinline__ float dpp_f(float x) {
  int r = __builtin_amdgcn_update_dpp(0, __builtin_bit_cast(int, x), CTRL, 0xF, 0xF, true);
  return __builtin_bit_cast(float, r);
}
__device__ __forceinline__ void gl16(const void* g, void* l) {
  __builtin_amdgcn_global_load_lds(
      (const __attribute__((address_space(1))) void*)g,
      (__attribute__((address_space(3))) void*)l, 16, 0, 0);
}

// ---------------- pre-pass: K/V -> fp16, V transposed+tile-blocked, ----------
// ---------------- XOR swizzle (16B slot ^= row&7) baked into layout ----------
__global__ __launch_bounds__(256, 4)
void dsattn_prep(const float* __restrict__ Kg, const float* __restrict__ Vg,
                 _Float16* __restrict__ Kh, _Float16* __restrict__ Vh) {
  __shared__ __align__(16) _Float16 T[64][72];   // V^T staging, 9216 B
  const int kt = (int)blockIdx.x;                // 0..31
  const int bh = (int)blockIdx.y;                // 0..15
  const int b = bh >> 3, h = bh & 7;
  const int tid = (int)threadIdx.x;
  const int sr = tid >> 2;                       // key row in tile, 0..63
  const int e0 = (tid & 3) << 4;                 // 16 elems per thread
  const int s = kt * KT + sr;

  // K: row-major [bh][s][e] halves, 128B rows, swizzled 16B slots
  {
    const float* kp = Kg + (((size_t)b * Sc + s) * Hc + h) * Ec + e0;
    float4 a0 = ((const float4*)kp)[0], a1 = ((const float4*)kp)[1];
    float4 a2 = ((const float4*)kp)[2], a3 = ((const float4*)kp)[3];
    union { h8 v; h2 c[4]; } u0, u1;
    u0.c[0] = pk2(a0.x, a0.y); u0.c[1] = pk2(a0.z, a0.w);
    u0.c[2] = pk2(a1.x, a1.y); u0.c[3] = pk2(a1.z, a1.w);
    u1.c[0] = pk2(a2.x, a2.y); u1.c[1] = pk2(a2.z, a2.w);
    u1.c[2] = pk2(a3.x, a3.y); u1.c[3] = pk2(a3.z, a3.w);
    char* out = (char*)Kh + (((size_t)bh * Sc + s) << 7);
    const int sl = e0 >> 3;
    const int rx = (sr & 7) << 4;
    *(h8*)(out + ((sl << 4) ^ rx)) = u0.v;
    *(h8*)(out + (((sl + 1) << 4) ^ rx)) = u1.v;
  }

  // V: transpose 64x64 tile via LDS, out layout [bh][kt][e][ks] swizzled
  {
    const float* vp = Vg + (((size_t)b * Sc + s) * Hc + h) * Ec + e0;
    float4 v0 = ((const float4*)vp)[0], v1 = ((const float4*)vp)[1];
    float4 v2 = ((const float4*)vp)[2], v3 = ((const float4*)vp)[3];
    const float ev[16] = {v0.x, v0.y, v0.z, v0.w, v1.x, v1.y, v1.z, v1.w,
                          v2.x, v2.y, v2.z, v2.w, v3.x, v3.y, v3.z, v3.w};
#pragma unroll
    for (int j = 0; j < 8; ++j) {
      h2 t = pk2(ev[2 * j], ev[2 * j + 1]);
      T[e0 + 2 * j][sr] = t[0];
      T[e0 + 2 * j + 1][sr] = t[1];
    }
  }
  __syncthreads();
  {
    const int er = tid >> 2;                     // e row 0..63
    const int k0 = (tid & 3) << 4;               // ks start
    h8 w0 = *(const h8*)&T[er][k0];
    h8 w1 = *(const h8*)&T[er][k0 + 8];
    char* out = (char*)Vh + (((size_t)bh * 32 + kt) << 13) + er * 128;
    const int sl = k0 >> 3;
    const int rx = (er & 7) << 4;
    *(h8*)(out + ((sl << 4) ^ rx)) = w0;
    *(h8*)(out + (((sl + 1) << 4) ^ rx)) = w1;
  }
}

// ---------------- main fwd: global_load_lds staging, 40960B LDS --------------
__global__ __launch_bounds__(256, 3)
void dsattn_fwd_main(const float* __restrict__ Qg, const _Float16* __restrict__ Kh,
                     const _Float16* __restrict__ Vh, const float* __restrict__ taug,
                     const float* __restrict__ deltag, float* __restrict__ Og,
                     _Float16* __restrict__ Opart, float* __restrict__ Lpart) {
  __shared__ __align__(16) _Float16 Ks[2][KT * 64];   // 16384 B
  __shared__ __align__(16) _Float16 Vt[2][Ec * 64];   // 16384 B
  __shared__ __align__(16) _Float16 Pb[4][16 * 64];   //  8192 B -> 40960 total

  const int tid = (int)threadIdx.x;
  const int wave = tid >> 6, lane = tid & 63;
  const int quad = lane >> 4, l16 = lane & 15;
  _Float16* pb = &Pb[wave][0];
  const int lo = l16 & 1;
  const int pbase = (lo ? 32 : 0) + (l16 & ~1);
  // swizzled half-unit offsets (rows read by this lane always have row&7==l16&7)
  const int kx = (l16 & 7) << 3;
  const int koff0 = (quad * 8) ^ kx;
  const int koff1 = (quad * 8 + 32) ^ kx;

  h8 onesf;
#pragma unroll
  for (int j = 0; j < 8; ++j) onesf[j] = (_Float16)1.0f;

  for (int it = (int)blockIdx.x; it < NIT; it += (int)gridDim.x) {
    // XCD-paired decode: blocks with the same (bid%8) share 2 bh -> L2 locality
    const int xcd = it & 7;
    const int r_ = it >> 3;                 // < 80
    const int bh = (xcd << 1) | (r_ & 1);
    const int e = r_ >> 1;                  // < 40
    const int qt = d_eqt[e], c0 = d_ec0[e];
    const int ntiles = 2 * qt + 2;
    const int nch = (ntiles + CH - 1) / CH;
    const int ktBeg = c0 * CH;
    const int ktEnd = min(ktBeg + CH - 1, ntiles - 1);
    const int q0 = qt * QTL;
    const int b = bh >> 3, h = bh & 7;
    const float ct = taug[b] * (SCALE * LOG2E);

    // ---- Q A-fragments ----
    h8 qfrag[2][2];
#pragma unroll
    for (int f = 0; f < 2; ++f)
#pragma unroll
      for (int kk = 0; kk < 2; ++kk) {
        const float* qp = Qg + (((size_t)b * Lc + q0 + 32 * wave + 16 * f + l16) * Hc + h) * Ec
                         + quad * 8 + kk * 32;
        const float4* p = (const float4*)qp;
        union { h8 v; h2 c[4]; } u;
        float4 a0 = p[0], a1 = p[1];
        u.c[0] = pk2(a0.x, a0.y); u.c[1] = pk2(a0.z, a0.w);
        u.c[2] = pk2(a1.x, a1.y); u.c[3] = pk2(a1.z, a1.w);
        qfrag[f][kk] = u.v;
      }

    f32x4 Oacc[2][4], Osum[2];
#pragma unroll
    for (int f = 0; f < 2; ++f) {
#pragma unroll
      for (int nt = 0; nt < 4; ++nt) Oacc[f][nt] = (f32x4){0.f, 0.f, 0.f, 0.f};
      Osum[f] = (f32x4){0.f, 0.f, 0.f, 0.f};
    }
    float dcur[4];

    __syncthreads();   // previous item's LDS reads complete before restaging

    // ---- prologue: async-stage tile ktBeg into buffer 0 ----
    {
      const char* kg = (const char*)Kh + (((size_t)bh * Sc + (size_t)ktBeg * KT) << 7)
                       + wave * 2048 + lane * 16;
      const char* vg = (const char*)Vh + (((size_t)bh * 32 + ktBeg) << 13)
                       + wave * 2048 + lane * 16;
      char* kl = (char*)&Ks[0][0] + wave * 2048;
      char* vl = (char*)&Vt[0][0] + wave * 2048;
      gl16(kg, kl); gl16(kg + 1024, kl + 1024);
      gl16(vg, vl); gl16(vg + 1024, vl + 1024);
#pragma unroll
      for (int nt = 0; nt < 4; ++nt)
        dcur[nt] = deltag[(size_t)b * Sc + ktBeg * KT + nt * 16 + l16] * (SCALE * LOG2E);
    }

    for (int kt = ktBeg; kt <= ktEnd; ++kt) {
      const int cur = (kt - ktBeg) & 1;
      const bool pf = (kt < ktEnd);
      const int kbase = kt * KT;

      __syncthreads();   // buffer cur ready (compiler drains vmcnt at barrier)

      // ---- async-prefetch kt+1 into the other buffer ----
      float dn[4];
      if (pf) {
        const char* kg = (const char*)Kh + (((size_t)bh * Sc + (size_t)(kt + 1) * KT) << 7)
                         + wave * 2048 + lane * 16;
        const char* vg = (const char*)Vh + (((size_t)bh * 32 + kt + 1) << 13)
                         + wave * 2048 + lane * 16;
        char* kl = (char*)&Ks[cur ^ 1][0] + wave * 2048;
        char* vl = (char*)&Vt[cur ^ 1][0] + wave * 2048;
        gl16(kg, kl); gl16(kg + 1024, kl + 1024);
        gl16(vg, vl); gl16(vg + 1024, vl + 1024);
#pragma unroll
        for (int nt = 0; nt < 4; ++nt)
          dn[nt] = deltag[(size_t)b * Sc + (kt + 1) * KT + nt * 16 + l16];
      }

      const int wtop = q0 + 32 * wave + 31;
      if (kbase <= wtop) {
        // ---- per 16-row fragment: QK^T -> softmax -> PV (halved live S) ----
#pragma unroll
        for (int f = 0; f < 2; ++f) {
          f32x4 Sacc[4];
#pragma unroll
          for (int nt = 0; nt < 4; ++nt) Sacc[nt] = (f32x4){0.f, 0.f, 0.f, 0.f};
          __builtin_amdgcn_s_setprio(1);
#pragma unroll
          for (int kk = 0; kk < 2; ++kk) {
            const int ko = kk ? koff1 : koff0;
            h8 bf[4];
#pragma unroll
            for (int nt = 0; nt < 4; ++nt)
              bf[nt] = *(const h8*)&Ks[cur][(nt * 16 + l16) * 64 + ko];
#pragma unroll
            for (int nt = 0; nt < 4; ++nt)
              Sacc[nt] = __builtin_amdgcn_mfma_f32_16x16x32_f16(qfrag[f][kk], bf[nt], Sacc[nt], 0, 0, 0);
          }
          __builtin_amdgcn_s_setprio(0);

          const int fr0 = q0 + 32 * wave + 16 * f;
#pragma unroll
          for (int nt = 0; nt < 4; ++nt)
#pragma unroll
            for (int rr = 0; rr < 4; ++rr)
              Sacc[nt][rr] = Sacc[nt][rr] * ct + dcur[nt];
          if (kbase + 63 > fr0) {
#pragma unroll
            for (int nt = 0; nt < 4; ++nt) {
              const int key = kbase + nt * 16 + l16;
#pragma unroll
              for (int rr = 0; rr < 4; ++rr)
                if (key > fr0 + quad * 4 + rr) Sacc[nt][rr] = -1e30f;
            }
          }
#pragma unroll
          for (int nt = 0; nt < 4; ++nt)
#pragma unroll
            for (int rr = 0; rr < 4; ++rr)
              Sacc[nt][rr] = __builtin_amdgcn_exp2f(Sacc[nt][rr]);   // bounded

          // P -> Pb rows quad*4+rr (DPP xor1 pairing, packed h2, XOR slots)
#pragma unroll
          for (int rr = 0; rr < 4; ++rr) {
            float o0 = dpp_f<0xB1>(Sacc[0][rr]);
            float o1 = dpp_f<0xB1>(Sacc[1][rr]);
            float o2 = dpp_f<0xB1>(Sacc[2][rr]);
            float o3 = dpp_f<0xB1>(Sacc[3][rr]);
            h2 d0 = lo ? pk2(o2, Sacc[2][rr]) : pk2(Sacc[0][rr], o0);
            h2 d1 = lo ? pk2(o3, Sacc[3][rr]) : pk2(Sacc[1][rr], o1);
            const int row = (quad << 2) + rr;
            char* pr = (char*)pb + row * 128;
            const int rx = (row & 7) << 4;
            *(h2*)(pr + ((pbase * 2) ^ rx)) = d0;
            *(h2*)(pr + ((pbase * 2 + 32) ^ rx)) = d1;
          }
          asm volatile("s_waitcnt lgkmcnt(0)" ::: "memory");  // wave-local P RAW
          __builtin_amdgcn_sched_barrier(0);                  // rule #18 fence

          h8 af0 = *(const h8*)&pb[l16 * 64 + koff0];
          h8 af1 = *(const h8*)&pb[l16 * 64 + koff1];

          __builtin_amdgcn_s_setprio(1);
#pragma unroll
          for (int nt = 0; nt < 4; ++nt) {
            h8 vf0 = *(const h8*)&Vt[cur][(nt * 16 + l16) * 64 + koff0];
            Oacc[f][nt] = __builtin_amdgcn_mfma_f32_16x16x32_f16(af0, vf0, Oacc[f][nt], 0, 0, 0);
            h8 vf1 = *(const h8*)&Vt[cur][(nt * 16 + l16) * 64 + koff1];
            Oacc[f][nt] = __builtin_amdgcn_mfma_f32_16x16x32_f16(af1, vf1, Oacc[f][nt], 0, 0, 0);
          }
          Osum[f] = __builtin_amdgcn_mfma_f32_16x16x32_f16(af0, onesf, Osum[f], 0, 0, 0);
          Osum[f] = __builtin_amdgcn_mfma_f32_16x16x32_f16(af1, onesf, Osum[f], 0, 0, 0);
          __builtin_amdgcn_s_setprio(0);
        }
      }

      if (pf) {
#pragma unroll
        for (int nt = 0; nt < 4; ++nt) dcur[nt] = dn[nt] * (SCALE * LOG2E);
      }
    }

    // ---- epilogue ----
    if (nch == 1) {
#pragma unroll
      for (int f = 0; f < 2; ++f)
#pragma unroll
        for (int rr = 0; rr < 4; ++rr) {
          const int qrow = q0 + 32 * wave + 16 * f + (quad << 2) + rr;
          const float inv = 1.0f / Osum[f][rr];
          float* op = Og + (((size_t)b * Lc + qrow) * Hc + h) * Ec;
#pragma unroll
          for (int nt = 0; nt < 4; ++nt) op[nt * 16 + l16] = Oacc[f][nt][rr] * inv;
        }
    } else {
      // fragment-layout Opart: half index = (row*16 + l16)*4 + nt
      const int en = bh * EPB + d_qtbase[qt] + c0;
      _Float16* op = Opart + (size_t)en * (QTL * Ec);
#pragma unroll
      for (int f = 0; f < 2; ++f)
#pragma unroll
        for (int rr = 0; rr < 4; ++rr) {
          const int row = 32 * wave + 16 * f + (quad << 2) + rr;
          h2 a = pk2(Oacc[f][0][rr], Oacc[f][1][rr]);
          h2 bq = pk2(Oacc[f][2][rr], Oacc[f][3][rr]);
          uint2 w;
          w.x = __builtin_bit_cast(unsigned, a);
          w.y = __builtin_bit_cast(unsigned, bq);
          *(uint2*)(op + ((size_t)row * 16 + l16) * 4) = w;
          if (l16 == 0) Lpart[en * QTL + row] = Osum[f][rr];
        }
    }
  }
}

// ---------------- combine (qt >= CH/2 have nch >= 2), fragment layout --------
__global__ __launch_bounds__(256, 4)
void dsattn_comb_main(const _Float16* __restrict__ Opart, const float* __restrict__ Lpart,
                      float* __restrict__ Og) {
  const int qt = (CH / 2) + ((int)blockIdx.x >> 2);
  const int slab = (int)blockIdx.x & 3;
  const int bh = (int)blockIdx.y;
  const int b = bh >> 3, h = bh & 7;
  const int nch = (2 * qt + 1 + CH) / CH;
  const int e0 = bh * EPB + d_qtbase[qt];
  const int l16 = (int)threadIdx.x & 15;
  const int rg = (int)threadIdx.x >> 4;          // 0..15, 2 rows each

#pragma unroll
  for (int rr = 0; rr < 2; ++rr) {
    const int row = slab * 32 + rg * 2 + rr;
    float acc[4] = {0.f, 0.f, 0.f, 0.f};
    float l = 0.f;
    for (int c = 0; c < nch; ++c) {
      l += Lpart[(e0 + c) * QTL + row];
      uint2 w = *(const uint2*)(Opart + (size_t)(e0 + c) * (QTL * Ec)
                                + ((size_t)row * 16 + l16) * 4);
      h2 a = __builtin_bit_cast(h2, w.x);
      h2 bq = __builtin_bit_cast(h2, w.y);
      acc[0] += (float)a[0]; acc[1] += (float)a[1];
      acc[2] += (float)bq[0]; acc[3] += (float)bq[1];
    }
    const float inv = 1.0f / l;
    float* out = Og + (((size_t)b * Lc + qt * QTL + row) * Hc + h) * Ec;
#pragma unroll
    for (int nt = 0; nt < 4; ++nt) out[nt * 16 + l16] = acc[nt] * inv;
  }
}

// ---------------- monolithic fallback (no workspace): old proven path --------
__global__ __launch_bounds__(256, 2)
void dsattn_fwd_mono(const float* __restrict__ Qg, const float* __restrict__ Kg,
                     const float* __restrict__ Vg, const float* __restrict__ taug,
                     const float* __restrict__ deltag, float* __restrict__ Og) {
  constexpr int LDK = 72;
  __shared__ __align__(16) _Float16 Ks[2][KT * LDK];
  __shared__ __align__(16) _Float16 Vt[2][Ec * LDK];
  __shared__ __align__(16) _Float16 Pb[4][16 * LDK];

  const int tid = (int)threadIdx.x;
  const int wave = tid >> 6, lane = tid & 63;
  const int quad = lane >> 4, l16 = lane & 15;
  const int srow = tid >> 2;
  const int sec = (tid & 3) << 4;
  const int vrp = ((tid >> 3) + 4 * (tid & 7)) & 31;
  const int ve8 = (tid & 7) << 3;
  _Float16* pb = &Pb[wave][0];
  const int lo = l16 & 1;
  const int pbase = (lo ? 32 : 0) + (l16 & ~1);

  h8 onesf;
#pragma unroll
  for (int j = 0; j < 8; ++j) onesf[j] = (_Float16)1.0f;

  for (int wid = (int)blockIdx.x; wid < NQT * NBH; wid += (int)gridDim.x) {
    const int bh = wid & (NBH - 1);
    const int qt = NQT - 1 - (wid >> 4);
    const int ktEnd = 2 * qt + 1;
    const int q0 = qt * QTL;
    const int b = bh >> 3, h = bh & 7;
    const float ct = taug[b] * (SCALE * LOG2E);

    h8 qfrag[2][2];
#pragma unroll
    for (int f = 0; f < 2; ++f)
#pragma unroll
      for (int kk = 0; kk < 2; ++kk) {
        const float* qp = Qg + (((size_t)b * Lc + q0 + 32 * wave + 16 * f + l16) * Hc + h) * Ec
                         + quad * 8 + kk * 32;
        const float4* p = (const float4*)qp;
        union { h8 v; h2 c[4]; } u;
        float4 a0 = p[0], a1 = p[1];
        u.c[0] = pk2(a0.x, a0.y); u.c[1] = pk2(a0.z, a0.w);
        u.c[2] = pk2(a1.x, a1.y); u.c[3] = pk2(a1.z, a1.w);
        qfrag[f][kk] = u.v;
      }

    f32x4 Oacc[2][4], Osum[2];
#pragma unroll
    for (int f = 0; f < 2; ++f) {
#pragma unroll
      for (int nt = 0; nt < 4; ++nt) Oacc[f][nt] = (f32x4){0.f, 0.f, 0.f, 0.f};
      Osum[f] = (f32x4){0.f, 0.f, 0.f, 0.f};
    }
    float dcur[4];

    __syncthreads();

    {
      const float* kp = Kg + (((size_t)b * Sc + srow) * Hc + h) * Ec + sec;
      float4 c0v = ((const float4*)kp)[0], c1v = ((const float4*)kp)[1];
      float4 c2v = ((const float4*)kp)[2], c3v = ((const float4*)kp)[3];
      const float* vp0 = Vg + (((size_t)b * Sc + 2 * vrp) * Hc + h) * Ec + ve8;
      const float* vp1 = vp0 + Hc * Ec;
      float4 r00 = ((const float4*)vp0)[0], r01 = ((const float4*)vp0)[1];
      float4 r10 = ((const float4*)vp1)[0], r11 = ((const float4*)vp1)[1];
#pragma unroll
      for (int nt = 0; nt < 4; ++nt)
        dcur[nt] = deltag[(size_t)b * Sc + nt * 16 + l16] * (SCALE * LOG2E);
      union { h8 v; h2 c[4]; } w0, w1;
      w0.c[0] = pk2(c0v.x, c0v.y); w0.c[1] = pk2(c0v.z, c0v.w);
      w0.c[2] = pk2(c1v.x, c1v.y); w0.c[3] = pk2(c1v.z, c1v.w);
      w1.c[0] = pk2(c2v.x, c2v.y); w1.c[1] = pk2(c2v.z, c2v.w);
      w1.c[2] = pk2(c3v.x, c3v.y); w1.c[3] = pk2(c3v.z, c3v.w);
      *(h8*)&Ks[0][srow * LDK + sec] = w0.v;
      *(h8*)&Ks[0][srow * LDK + sec + 8] = w1.v;
      const float e0[8] = {r00.x, r00.y, r00.z, r00.w, r01.x, r01.y, r01.z, r01.w};
      const float e1[8] = {r10.x, r10.y, r10.z, r10.w, r11.x, r11.y, r11.z, r11.w};
#pragma unroll
      for (int j = 0; j < 8; ++j)
        *(h2*)&Vt[0][(ve8 + j) * LDK + 2 * vrp] = pk2(e0[j], e1[j]);
    }

    for (int kt = 0; kt <= ktEnd; ++kt) {
      const int cur = kt & 1;
      const bool pf = (kt < ktEnd);
      const int kbase = kt * KT;

      __syncthreads();

      float4 kn0, kn1, kn2, kn3, vn00, vn01, vn10, vn11;
      float dn[4];
      if (pf) {
        const int nb = (kt + 1) * KT;
        const float* kp = Kg + (((size_t)b * Sc + nb + srow) * Hc + h) * Ec + sec;
        kn0 = ((const float4*)kp)[0]; kn1 = ((const float4*)kp)[1];
        kn2 = ((const float4*)kp)[2]; kn3 = ((const float4*)kp)[3];
        const float* vp0 = Vg + (((size_t)b * Sc + nb + 2 * vrp) * Hc + h) * Ec + ve8;
        const float* vp1 = vp0 + Hc * Ec;
        vn00 = ((const float4*)vp0)[0]; vn01 = ((const float4*)vp0)[1];
        vn10 = ((const float4*)vp1)[0]; vn11 = ((const float4*)vp1)[1];
#pragma unroll
        for (int nt = 0; nt < 4; ++nt)
          dn[nt] = deltag[(size_t)b * Sc + nb + nt * 16 + l16];
      }

      const int wtop = q0 + 32 * wave + 31;
      if (kbase <= wtop) {
        f32x4 Sacc[2][4];
#pragma unroll
        for (int f = 0; f < 2; ++f)
#pragma unroll
          for (int nt = 0; nt < 4; ++nt) Sacc[f][nt] = (f32x4){0.f, 0.f, 0.f, 0.f};
#pragma unroll
        for (int kk = 0; kk < 2; ++kk) {
          h8 bf[4];
#pragma unroll
          for (int nt = 0; nt < 4; ++nt)
            bf[nt] = *(const h8*)&Ks[cur][(nt * 16 + l16) * LDK + quad * 8 + kk * 32];
#pragma unroll
          for (int f = 0; f < 2; ++f)
#pragma unroll
            for (int nt = 0; nt < 4; ++nt)
              Sacc[f][nt] = __builtin_amdgcn_mfma_f32_16x16x32_f16(qfrag[f][kk], bf[nt], Sacc[f][nt], 0, 0, 0);
        }

#pragma unroll
        for (int f = 0; f < 2; ++f) {
          const int fr0 = q0 + 32 * wave + 16 * f;
          float sv[4][4];
#pragma unroll
          for (int nt = 0; nt < 4; ++nt)
#pragma unroll
            for (int rr = 0; rr < 4; ++rr)
              sv[nt][rr] = Sacc[f][nt][rr] * ct + dcur[nt];
          if (kbase + 63 > fr0) {
#pragma unroll
            for (int nt = 0; nt < 4; ++nt) {
              const int key = kbase + nt * 16 + l16;
#pragma unroll
              for (int rr = 0; rr < 4; ++rr)
                if (key > fr0 + quad * 4 + rr) sv[nt][rr] = -1e30f;
            }
          }
#pragma unroll
          for (int nt = 0; nt < 4; ++nt)
#pragma unroll
            for (int rr = 0; rr < 4; ++rr)
              sv[nt][rr] = __builtin_amdgcn_exp2f(sv[nt][rr]);

#pragma unroll
          for (int rr = 0; rr < 4; ++rr) {
            float o0 = dpp_f<0xB1>(sv[0][rr]);
            float o1 = dpp_f<0xB1>(sv[1][rr]);
            float o2 = dpp_f<0xB1>(sv[2][rr]);
            float o3 = dpp_f<0xB1>(sv[3][rr]);
            h2 d0 = lo ? pk2(o2, sv[2][rr]) : pk2(sv[0][rr], o0);
            h2 d1 = lo ? pk2(o3, sv[3][rr]) : pk2(sv[1][rr], o1);
            _Float16* pp = &pb[((quad << 2) + rr) * LDK + pbase];
            *(h2*)pp = d0;
            *(h2*)(pp + 16) = d1;
          }
          asm volatile("s_waitcnt lgkmcnt(0)" ::: "memory");

          h8 af0 = *(const h8*)&pb[l16 * LDK + quad * 8];
          h8 af1 = *(const h8*)&pb[l16 * LDK + quad * 8 + 32];

#pragma unroll
          for (int nt = 0; nt < 4; ++nt) {
            h8 vf0 = *(const h8*)&Vt[cur][(nt * 16 + l16) * LDK + quad * 8];
            Oacc[f][nt] = __builtin_amdgcn_mfma_f32_16x16x32_f16(af0, vf0, Oacc[f][nt], 0, 0, 0);
            h8 vf1 = *(const h8*)&Vt[cur][(nt * 16 + l16) * LDK + quad * 8 + 32];
            Oacc[f][nt] = __builtin_amdgcn_mfma_f32_16x16x32_f16(af1, vf1, Oacc[f][nt], 0, 0, 0);
          }
          Osum[f] = __builtin_amdgcn_mfma_f32_16x16x32_f16(af0, onesf, Osum[f], 0, 0, 0);
          Osum[f] = __builtin_amdgcn_mfma_f32_16x16x32_f16(af1, onesf, Osum[f], 0, 0, 0);
        }
      }

      if (pf) {
        _Float16* ksn = &Ks[cur ^ 1][0];
        _Float16* vtn = &Vt[cur ^ 1][0];
        union { h8 v; h2 c[4]; } w0, w1;
        w0.c[0] = pk2(kn0.x, kn0.y); w0.c[1] = pk2(kn0.z, kn0.w);
        w0.c[2] = pk2(kn1.x, kn1.y); w0.c[3] = pk2(kn1.z, kn1.w);
        w1.c[0] = pk2(kn2.x, kn2.y); w1.c[1] = pk2(kn2.z, kn2.w);
        w1.c[2] = pk2(kn3.x, kn3.y); w1.c[3] = pk2(kn3.z, kn3.w);
        *(h8*)&ksn[srow * LDK + sec] = w0.v;
        *(h8*)&ksn[srow * LDK + sec + 8] = w1.v;
        const float e0[8] = {vn00.x, vn00.y, vn00.z, vn00.w, vn01.x, vn01.y, vn01.z, vn01.w};
        const float e1[8] = {vn10.x, vn10.y, vn10.z, vn10.w, vn11.x, vn11.y, vn11.z, vn11.w};
#pragma unroll
        for (int j = 0; j < 8; ++j)
          *(h2*)&vtn[(ve8 + j) * LDK + 2 * vrp] = pk2(e0[j], e1[j]);
#pragma unroll
        for (int nt = 0; nt < 4; ++nt) dcur[nt] = dn[nt] * (SCALE * LOG2E);
      }
    }

#pragma unroll
    for (int f = 0; f < 2; ++f)
#pragma unroll
      for (int rr = 0; rr < 4; ++rr) {
        const int qrow = q0 + 32 * wave + 16 * f + (quad << 2) + rr;
        const float inv = 1.0f / Osum[f][rr];
        float* op = Og + (((size_t)b * Lc + qrow) * Hc + h) * Ec;
#pragma unroll
        for (int nt = 0; nt < 4; ++nt) op[nt * 16 + l16] = Oacc[f][nt][rr] * inv;
      }
  }
}

extern "C" void kernel_launch(void* const* d_in, const int* in_sizes, int n_in,
                              void* d_out, int out_size, void* d_ws, size_t ws_size,
                              hipStream_t stream) {
  const float* Q = (const float*)d_in[0];
  const float* K = (const float*)d_in[1];
  const float* V = (const float*)d_in[2];
  const float* tau = (const float*)d_in[3];
  const float* delta = (const float*)d_in[4];
  float* O = (float*)d_out;

  const size_t needOp = (size_t)NIT * QTL * Ec * 2;       // 10.49 MB
  const size_t needLp = (size_t)NIT * QTL * 4;            //  0.33 MB
  const size_t needKh = (size_t)NBH * Sc * Ec * 2;        //  4.19 MB
  const size_t needVh = needKh;                           //  4.19 MB
  const size_t need = needOp + needLp + needKh + needVh;  // 19.2 MB

  if (ws_size >= need) {
    _Float16* Opart = (_Float16*)d_ws;
    float* Lpart = (float*)((char*)d_ws + needOp);
    _Float16* Kh = (_Float16*)((char*)d_ws + needOp + needLp);
    _Float16* Vh = (_Float16*)((char*)d_ws + needOp + needLp + needKh);
    dsattn_prep<<<dim3(Sc / KT, NBH), 256, 0, stream>>>(K, V, Kh, Vh);
    dsattn_fwd_main<<<dim3(NIT), 256, 0, stream>>>(Q, Kh, Vh, tau, delta, O,
                                                   Opart, Lpart);
    dsattn_comb_main<<<dim3((NQT - CH / 2) * 4, NBH), 256, 0, stream>>>(Opart, Lpart, O);
  } else {
    dsattn_fwd_mono<<<dim3(NQT * NBH), 256, 0, stream>>>(Q, K, V, tau, delta, O);
  }
}